// Round 10
// baseline (422.102 us; speedup 1.0000x reference)
//
#include <hip/hip_runtime.h>

// GCN forward: h = relu(spmm(x@w1)+b1); out = spmm(h@w2)+b2
// CSR built per launch (bucket partition + per-bucket counting sort).
// Intermediates bf16-packed. GEMMs: register MFMA, 16-row waves (r9 latency fix).
// SpMM: half-wave(32-lane)/quarter-wave(16-lane) per row, 8B gathers (r9).

typedef unsigned int uint;
typedef unsigned short ushort;
using bf16x8 = __attribute__((ext_vector_type(8))) short;
using f32x4  = __attribute__((ext_vector_type(4))) float;

union U8 { bf16x8 v; uint4 q; };

#define CHUNK 2048    // edges per partition block
#define BW    128     // rows per bucket

__device__ inline uint f2bf(float f) {
  uint u = __float_as_uint(f);
  return (u + 0x7fffu + ((u >> 16) & 1u)) >> 16;   // RNE
}
__device__ inline uint pkbf(float lo, float hi) { return f2bf(lo) | (f2bf(hi) << 16); }
__device__ inline float bf_lo(uint u) { return __uint_as_float(u << 16); }
__device__ inline float bf_hi(uint u) { return __uint_as_float(u & 0xffff0000u); }

// ---------------- weight transpose+cast (fused, tiny) ----------------
__global__ void k_tr_w(const float* __restrict__ w1, ushort* __restrict__ w1t,
                       const float* __restrict__ w2, ushort* __restrict__ w2t) {
  int idx = blockIdx.x * 256 + threadIdx.x;
  if (idx < 32768) {               // 256x128
    int k = idx >> 7, n = idx & 127;
    w1t[n * 256 + k] = (ushort)f2bf(w1[idx]);
  } else {
    int j = idx - 32768;           // 128x64
    if (j < 8192) {
      int k = j >> 6, n = j & 63;
      w2t[n * 128 + k] = (ushort)f2bf(w2[j]);
    }
  }
}

// ---------------- P1: per-chunk histogram over row-buckets ----------------
__global__ __launch_bounds__(256)
void k_p1_hist(const int* __restrict__ row, int* __restrict__ bh,
               int nb, int nblk, int ne) {
  __shared__ int hist[1024];
  int t = threadIdx.x;
  for (int i = t; i < nb; i += 256) hist[i] = 0;
  __syncthreads();
  int base = blockIdx.x * CHUNK;
  int end  = min(base + CHUNK, ne);
  for (int i = base + t; i < end; i += 256)
    atomicAdd(&hist[row[i] >> 7], 1);
  __syncthreads();
  for (int i = t; i < nb; i += 256)
    bh[(size_t)i * nblk + blockIdx.x] = hist[i];   // transposed: [bucket][chunk]
}

// ---------------- P2a: per-bucket exclusive scan across chunks ----------------
__global__ __launch_bounds__(1024)
void k_p2a(int* __restrict__ bh, int* __restrict__ tot, int nblk) {
  __shared__ int sd[1024];
  int g = blockIdx.x, t = threadIdx.x;
  int v = (t < nblk) ? bh[(size_t)g * nblk + t] : 0;
  sd[t] = v;
  __syncthreads();
  for (int o = 1; o < 1024; o <<= 1) {
    int x = (t >= o) ? sd[t - o] : 0;
    __syncthreads();
    sd[t] += x;
    __syncthreads();
  }
  if (t < nblk) bh[(size_t)g * nblk + t] = sd[t] - v;
  if (t == 1023) tot[g] = sd[1023];
}

// ---------------- P2b: exclusive scan of bucket totals -> bucketBase ----------------
__global__ __launch_bounds__(1024)
void k_p2b(const int* __restrict__ tot, int* __restrict__ bucketBase, int nb) {
  __shared__ int sd[1024];
  int t = threadIdx.x;
  int v = (t < nb) ? tot[t] : 0;
  sd[t] = v;
  __syncthreads();
  for (int o = 1; o < 1024; o <<= 1) {
    int x = (t >= o) ? sd[t - o] : 0;
    __syncthreads();
    sd[t] += x;
    __syncthreads();
  }
  if (t < nb) bucketBase[t] = sd[t] - v;
}

// ---------------- P3: partition edges into bucket segments ----------------
__global__ __launch_bounds__(256)
void k_p3_part(const int* __restrict__ row, const int* __restrict__ col,
               const float* __restrict__ vals, const int* __restrict__ bh,
               const int* __restrict__ bucketBase, uint2* __restrict__ tmp,
               int nb, int nblk, int ne) {
  __shared__ int cur[1024];
  int t = threadIdx.x, blk = blockIdx.x;
  for (int i = t; i < nb; i += 256)
    cur[i] = bucketBase[i] + bh[(size_t)i * nblk + blk];
  __syncthreads();
  int base = blk * CHUNK;
  int end  = min(base + CHUNK, ne);
  for (int i = base + t; i < end; i += 256) {
    int r = row[i];
    int p = atomicAdd(&cur[r >> 7], 1);
    tmp[p] = make_uint2(((uint)(r & 127) << 17) | (uint)col[i],
                        __float_as_uint(vals[i]));
  }
}

// ---------------- P4: per-bucket counting sort; emits rp + final edges ----------------
__global__ __launch_bounds__(256)
void k_p4_sort(const uint2* __restrict__ tmp, const int* __restrict__ bucketBase,
               int* __restrict__ rp, uint2* __restrict__ edges,
               int ne, int nb) {
  __shared__ int hist[128];
  __shared__ int cur[128];
  int g = blockIdx.x, t = threadIdx.x;
  int base = bucketBase[g];
  int end  = (g + 1 < nb) ? bucketBase[g + 1] : ne;
  if (t < 128) hist[t] = 0;
  __syncthreads();
  for (int i = base + t; i < end; i += 256)
    atomicAdd(&hist[tmp[i].x >> 17], 1);
  __syncthreads();
  int v = (t < 128) ? hist[t] : 0;
  for (int o = 1; o < 128; o <<= 1) {
    int x = (t < 128 && t >= o) ? hist[t - o] : 0;
    __syncthreads();
    if (t < 128) hist[t] += x;
    __syncthreads();
  }
  if (t < 128) {
    int excl = hist[t] - v;
    rp[(g << 7) + t] = base + excl;   // rows >= N get rp = segment end (= NE at tail)
    cur[t] = base + excl;
  }
  __syncthreads();
  for (int i = base + t; i < end; i += 256) {
    uint2 ev = tmp[i];
    int lr = (int)(ev.x >> 17);
    int p = atomicAdd(&cur[lr], 1);
    edges[p] = make_uint2(ev.x & 0x1FFFFu, ev.y);
  }
}

// ---------------- GEMM1 (MFMA): h_bf16[M,128] = x[M,256] @ w1[256,128] ----------------
// Block: 32 rows x 128 cols; wave = 16 rows x 64 cols (deep occupancy, r9).
__global__ __launch_bounds__(256)
void gemm1_mfma(const float* __restrict__ A, const ushort* __restrict__ Bt,
                uint* __restrict__ C, int M) {
  const int tid  = threadIdx.x;
  const int wid  = tid >> 6;
  const int lane = tid & 63;
  const int lr   = lane & 15;
  const int lk   = lane >> 4;
  const int m0   = blockIdx.x * 32 + (wid >> 1) * 16;
  const int n0   = (wid & 1) * 64;            // col offset, 4 nf frags

  f32x4 acc[4];
#pragma unroll
  for (int nf = 0; nf < 4; ++nf) acc[nf] = (f32x4){0.f, 0.f, 0.f, 0.f};

  const int row0 = min(m0 + lr, M - 1);
  const float*  ap = A + (size_t)row0 * 256 + lk * 8;
  const ushort* bp = Bt + (n0 + lr) * 256 + lk * 8;

#pragma unroll
  for (int kk = 0; kk < 8; ++kk) {
    float4 x0 = *(const float4*)(ap + kk * 32);
    float4 x1 = *(const float4*)(ap + kk * 32 + 4);
    U8 a;
    a.q = make_uint4(pkbf(x0.x, x0.y), pkbf(x0.z, x0.w), pkbf(x1.x, x1.y), pkbf(x1.z, x1.w));
    bf16x8 b[4];
#pragma unroll
    for (int nf = 0; nf < 4; ++nf)
      b[nf] = *(const bf16x8*)(bp + nf * 4096 + kk * 32);   // nf stride = 16 B-rows
#pragma unroll
    for (int nf = 0; nf < 4; ++nf)
      acc[nf] = __builtin_amdgcn_mfma_f32_16x16x32_bf16(a.v, b[nf], acc[nf], 0, 0, 0);
  }

  const bool evenl = (lr & 1) == 0;
#pragma unroll
  for (int nf = 0; nf < 4; ++nf)
#pragma unroll
    for (int j = 0; j < 4; ++j) {
      float own = acc[nf][j];
      float oth = __shfl_xor(own, 1);
      int row = m0 + lk * 4 + j;
      if (evenl && row < M)
        C[(size_t)row * 64 + (n0 >> 1) + nf * 8 + (lr >> 1)] = pkbf(own, oth);
    }
}

// ---------------- GEMM2 (MFMA): h2_bf16[M,64] = agg_bf16[M,128] @ w2[128,64] ----------------
// Block: 32 rows x 64 cols; wave = 16 rows x 32 cols.
__global__ __launch_bounds__(256)
void gemm2_mfma(const uint* __restrict__ A, const ushort* __restrict__ Bt,
                uint* __restrict__ C, int M) {
  const int tid  = threadIdx.x;
  const int wid  = tid >> 6;
  const int lane = tid & 63;
  const int lr   = lane & 15;
  const int lk   = lane >> 4;
  const int m0   = blockIdx.x * 32 + (wid >> 1) * 16;
  const int n0   = (wid & 1) * 32;            // col offset, 2 nf frags

  f32x4 acc[2];
#pragma unroll
  for (int nf = 0; nf < 2; ++nf) acc[nf] = (f32x4){0.f, 0.f, 0.f, 0.f};

  const int row0 = min(m0 + lr, M - 1);
  const ushort* A16 = (const ushort*)A;
  const ushort* ap  = A16 + (size_t)row0 * 128 + lk * 8;
  const ushort* bp  = Bt + (n0 + lr) * 128 + lk * 8;

#pragma unroll
  for (int kk = 0; kk < 4; ++kk) {
    bf16x8 a = *(const bf16x8*)(ap + kk * 32);
    bf16x8 b[2];
#pragma unroll
    for (int nf = 0; nf < 2; ++nf)
      b[nf] = *(const bf16x8*)(bp + nf * 2048 + kk * 32);
#pragma unroll
    for (int nf = 0; nf < 2; ++nf)
      acc[nf] = __builtin_amdgcn_mfma_f32_16x16x32_bf16(a, b[nf], acc[nf], 0, 0, 0);
  }

  const bool evenl = (lr & 1) == 0;
#pragma unroll
  for (int nf = 0; nf < 2; ++nf)
#pragma unroll
    for (int j = 0; j < 4; ++j) {
      float own = acc[nf][j];
      float oth = __shfl_xor(own, 1);
      int row = m0 + lk * 4 + j;
      if (evenl && row < M)
        C[(size_t)row * 32 + (n0 >> 1) + nf * 8 + (lr >> 1)] = pkbf(own, oth);
    }
}

// ---------------- SPMM1 + relu(+b1): half-wave (32 lanes) per row, 8B gathers ----------------
__global__ __launch_bounds__(256)
void k_spmm1(const int* __restrict__ rp, const uint2* __restrict__ edges,
             const uint2* __restrict__ hx, const float* __restrict__ b1,
             uint2* __restrict__ agg, int n) {
  int r = blockIdx.x * 8 + (threadIdx.x >> 5);
  if (r >= n) return;
  int l = threadIdx.x & 31;            // feats 4l..4l+3 (uint2 = 4 bf16)
  int s = rp[r], e = rp[r + 1];
  float a0 = 0.f, a1 = 0.f, a2 = 0.f, a3 = 0.f;
  int t = s;
  for (; t + 8 <= e; t += 8) {
    uint2 e0 = edges[t + 0], e1 = edges[t + 1], e2 = edges[t + 2], e3 = edges[t + 3];
    uint2 e4 = edges[t + 4], e5 = edges[t + 5], e6 = edges[t + 6], e7 = edges[t + 7];
    uint2 u0 = hx[(size_t)e0.x * 32 + l];
    uint2 u1 = hx[(size_t)e1.x * 32 + l];
    uint2 u2 = hx[(size_t)e2.x * 32 + l];
    uint2 u3 = hx[(size_t)e3.x * 32 + l];
    uint2 u4 = hx[(size_t)e4.x * 32 + l];
    uint2 u5 = hx[(size_t)e5.x * 32 + l];
    uint2 u6 = hx[(size_t)e6.x * 32 + l];
    uint2 u7 = hx[(size_t)e7.x * 32 + l];
    float v0 = __uint_as_float(e0.y), v1 = __uint_as_float(e1.y);
    float v2 = __uint_as_float(e2.y), v3 = __uint_as_float(e3.y);
    float v4 = __uint_as_float(e4.y), v5 = __uint_as_float(e5.y);
    float v6 = __uint_as_float(e6.y), v7 = __uint_as_float(e7.y);
    a0 = fmaf(v0, bf_lo(u0.x), a0); a1 = fmaf(v0, bf_hi(u0.x), a1);
    a2 = fmaf(v0, bf_lo(u0.y), a2); a3 = fmaf(v0, bf_hi(u0.y), a3);
    a0 = fmaf(v1, bf_lo(u1.x), a0); a1 = fmaf(v1, bf_hi(u1.x), a1);
    a2 = fmaf(v1, bf_lo(u1.y), a2); a3 = fmaf(v1, bf_hi(u1.y), a3);
    a0 = fmaf(v2, bf_lo(u2.x), a0); a1 = fmaf(v2, bf_hi(u2.x), a1);
    a2 = fmaf(v2, bf_lo(u2.y), a2); a3 = fmaf(v2, bf_hi(u2.y), a3);
    a0 = fmaf(v3, bf_lo(u3.x), a0); a1 = fmaf(v3, bf_hi(u3.x), a1);
    a2 = fmaf(v3, bf_lo(u3.y), a2); a3 = fmaf(v3, bf_hi(u3.y), a3);
    a0 = fmaf(v4, bf_lo(u4.x), a0); a1 = fmaf(v4, bf_hi(u4.x), a1);
    a2 = fmaf(v4, bf_lo(u4.y), a2); a3 = fmaf(v4, bf_hi(u4.y), a3);
    a0 = fmaf(v5, bf_lo(u5.x), a0); a1 = fmaf(v5, bf_hi(u5.x), a1);
    a2 = fmaf(v5, bf_lo(u5.y), a2); a3 = fmaf(v5, bf_hi(u5.y), a3);
    a0 = fmaf(v6, bf_lo(u6.x), a0); a1 = fmaf(v6, bf_hi(u6.x), a1);
    a2 = fmaf(v6, bf_lo(u6.y), a2); a3 = fmaf(v6, bf_hi(u6.y), a3);
    a0 = fmaf(v7, bf_lo(u7.x), a0); a1 = fmaf(v7, bf_hi(u7.x), a1);
    a2 = fmaf(v7, bf_lo(u7.y), a2); a3 = fmaf(v7, bf_hi(u7.y), a3);
  }
  for (; t < e; ++t) {
    uint2 e0 = edges[t];
    uint2 u0 = hx[(size_t)e0.x * 32 + l];
    float v0 = __uint_as_float(e0.y);
    a0 = fmaf(v0, bf_lo(u0.x), a0); a1 = fmaf(v0, bf_hi(u0.x), a1);
    a2 = fmaf(v0, bf_lo(u0.y), a2); a3 = fmaf(v0, bf_hi(u0.y), a3);
  }
  float4 bb = ((const float4*)b1)[l];
  float r0 = fmaxf(a0 + bb.x, 0.f);
  float r1 = fmaxf(a1 + bb.y, 0.f);
  float r2 = fmaxf(a2 + bb.z, 0.f);
  float r3 = fmaxf(a3 + bb.w, 0.f);
  agg[(size_t)r * 32 + l] = make_uint2(pkbf(r0, r1), pkbf(r2, r3));
}

// ---------------- SPMM2 + b2: quarter-wave (16 lanes) per row, 8B gathers ----------------
__global__ __launch_bounds__(256)
void k_spmm2(const int* __restrict__ rp, const uint2* __restrict__ edges,
             const uint2* __restrict__ hx2, const float* __restrict__ b2,
             float* __restrict__ out, int n) {
  int r = blockIdx.x * 16 + (threadIdx.x >> 4);
  if (r >= n) return;
  int l = threadIdx.x & 15;            // feats 4l..4l+3
  int s = rp[r], e = rp[r + 1];
  float a0 = 0.f, a1 = 0.f, a2 = 0.f, a3 = 0.f;
  int t = s;
  for (; t + 8 <= e; t += 8) {
    uint2 e0 = edges[t + 0], e1 = edges[t + 1], e2 = edges[t + 2], e3 = edges[t + 3];
    uint2 e4 = edges[t + 4], e5 = edges[t + 5], e6 = edges[t + 6], e7 = edges[t + 7];
    uint2 u0 = hx2[(size_t)e0.x * 16 + l];
    uint2 u1 = hx2[(size_t)e1.x * 16 + l];
    uint2 u2 = hx2[(size_t)e2.x * 16 + l];
    uint2 u3 = hx2[(size_t)e3.x * 16 + l];
    uint2 u4 = hx2[(size_t)e4.x * 16 + l];
    uint2 u5 = hx2[(size_t)e5.x * 16 + l];
    uint2 u6 = hx2[(size_t)e6.x * 16 + l];
    uint2 u7 = hx2[(size_t)e7.x * 16 + l];
    float v0 = __uint_as_float(e0.y), v1 = __uint_as_float(e1.y);
    float v2 = __uint_as_float(e2.y), v3 = __uint_as_float(e3.y);
    float v4 = __uint_as_float(e4.y), v5 = __uint_as_float(e5.y);
    float v6 = __uint_as_float(e6.y), v7 = __uint_as_float(e7.y);
    a0 = fmaf(v0, bf_lo(u0.x), a0); a1 = fmaf(v0, bf_hi(u0.x), a1);
    a2 = fmaf(v0, bf_lo(u0.y), a2); a3 = fmaf(v0, bf_hi(u0.y), a3);
    a0 = fmaf(v1, bf_lo(u1.x), a0); a1 = fmaf(v1, bf_hi(u1.x), a1);
    a2 = fmaf(v1, bf_lo(u1.y), a2); a3 = fmaf(v1, bf_hi(u1.y), a3);
    a0 = fmaf(v2, bf_lo(u2.x), a0); a1 = fmaf(v2, bf_hi(u2.x), a1);
    a2 = fmaf(v2, bf_lo(u2.y), a2); a3 = fmaf(v2, bf_hi(u2.y), a3);
    a0 = fmaf(v3, bf_lo(u3.x), a0); a1 = fmaf(v3, bf_hi(u3.x), a1);
    a2 = fmaf(v3, bf_lo(u3.y), a2); a3 = fmaf(v3, bf_hi(u3.y), a3);
    a0 = fmaf(v4, bf_lo(u4.x), a0); a1 = fmaf(v4, bf_hi(u4.x), a1);
    a2 = fmaf(v4, bf_lo(u4.y), a2); a3 = fmaf(v4, bf_hi(u4.y), a3);
    a0 = fmaf(v5, bf_lo(u5.x), a0); a1 = fmaf(v5, bf_hi(u5.x), a1);
    a2 = fmaf(v5, bf_lo(u5.y), a2); a3 = fmaf(v5, bf_hi(u5.y), a3);
    a0 = fmaf(v6, bf_lo(u6.x), a0); a1 = fmaf(v6, bf_hi(u6.x), a1);
    a2 = fmaf(v6, bf_lo(u6.y), a2); a3 = fmaf(v6, bf_hi(u6.y), a3);
    a0 = fmaf(v7, bf_lo(u7.x), a0); a1 = fmaf(v7, bf_hi(u7.x), a1);
    a2 = fmaf(v7, bf_lo(u7.y), a2); a3 = fmaf(v7, bf_hi(u7.y), a3);
  }
  for (; t < e; ++t) {
    uint2 e0 = edges[t];
    uint2 u0 = hx2[(size_t)e0.x * 16 + l];
    float v0 = __uint_as_float(e0.y);
    a0 = fmaf(v0, bf_lo(u0.x), a0); a1 = fmaf(v0, bf_hi(u0.x), a1);
    a2 = fmaf(v0, bf_lo(u0.y), a2); a3 = fmaf(v0, bf_hi(u0.y), a3);
  }
  float4 bb = ((const float4*)b2)[l];
  ((float4*)out)[(size_t)r * 16 + l] =
      make_float4(a0 + bb.x, a1 + bb.y, a2 + bb.z, a3 + bb.w);
}

extern "C" void kernel_launch(void* const* d_in, const int* in_sizes, int n_in,
                              void* d_out, int out_size, void* d_ws, size_t ws_size,
                              hipStream_t stream) {
  const float* x        = (const float*)d_in[0];
  const float* w1       = (const float*)d_in[1];
  const float* b1       = (const float*)d_in[2];
  const float* w2       = (const float*)d_in[3];
  const float* b2       = (const float*)d_in[4];
  const int*   adj_row  = (const int*)d_in[5];
  const int*   adj_col  = (const int*)d_in[6];
  const float* adj_vals = (const float*)d_in[7];
  float* out = (float*)d_out;

  const int N  = in_sizes[0] / 256;   // 100000
  const int NE = in_sizes[5];         // 1600000

  const int NB   = (N + BW - 1) / BW;          // 782 row-buckets
  const int NBLK = (NE + CHUNK - 1) / CHUNK;   // 782 partition chunks

  char* p = (char*)d_ws;
  auto carve = [&](size_t bytes) {
    char* r = p;
    p += (bytes + 255) & ~(size_t)255;
    return (void*)r;
  };
  uint*   h      = (uint*)  carve((size_t)N * 64 * 4);          // bf16 [N][128]
  uint*   agg    = (uint*)  carve((size_t)N * 64 * 4);          // bf16 [N][128]
  uint2*  edges  = (uint2*) carve((size_t)NE * 8);              // {col, val}
  uint2*  tmp    = (uint2*) carve((size_t)NE * 8);              // bucket-partitioned
  int*    rp     = (int*)   carve(((size_t)NB * BW + 64) * 4);  // row ptrs (rp[N] valid)
  int*    bh     = (int*)   carve((size_t)NB * NBLK * 4);       // [bucket][chunk] hist
  int*    tot    = (int*)   carve((size_t)NB * 4 + 256);
  int*    bbase  = (int*)   carve((size_t)NB * 4 + 256);
  ushort* w1t    = (ushort*)carve(128 * 256 * 2);               // bf16 [128][256]
  ushort* w2t    = (ushort*)carve(64 * 128 * 2);                // bf16 [64][128]
  uint*   h2     = h;                                           // h dead after spmm1

  hipLaunchKernelGGL(k_tr_w,    dim3(160),             dim3(256),  0, stream, w1, w1t, w2, w2t);
  hipLaunchKernelGGL(k_p1_hist, dim3(NBLK),            dim3(256),  0, stream, adj_row, bh, NB, NBLK, NE);
  hipLaunchKernelGGL(k_p2a,     dim3(NB),              dim3(1024), 0, stream, bh, tot, NBLK);
  hipLaunchKernelGGL(k_p2b,     dim3(1),               dim3(1024), 0, stream, tot, bbase, NB);
  hipLaunchKernelGGL(k_p3_part, dim3(NBLK),            dim3(256),  0, stream,
                     adj_row, adj_col, adj_vals, bh, bbase, tmp, NB, NBLK, NE);
  hipLaunchKernelGGL(k_p4_sort, dim3(NB),              dim3(256),  0, stream,
                     tmp, bbase, rp, edges, NE, NB);

  hipLaunchKernelGGL(gemm1_mfma, dim3((N + 31) / 32),  dim3(256), 0, stream, x, w1t, h, N);
  hipLaunchKernelGGL(k_spmm1,    dim3((N + 7) / 8),    dim3(256), 0, stream,
                     rp, edges, (const uint2*)h, b1, (uint2*)agg, N);
  hipLaunchKernelGGL(gemm2_mfma, dim3((N + 31) / 32),  dim3(256), 0, stream, agg, w2t, h2, N);
  hipLaunchKernelGGL(k_spmm2,    dim3((N + 15) / 16),  dim3(256), 0, stream,
                     rp, edges, (const uint2*)h2, b2, out, N);
}